// Round 11
// baseline (1083.619 us; speedup 1.0000x reference)
//
#include <hip/hip_runtime.h>
#include <hip/hip_fp16.h>
#include <cmath>

typedef __attribute__((ext_vector_type(8))) _Float16 f16x8;
typedef __attribute__((ext_vector_type(4))) float f32x4;

__device__ __forceinline__ unsigned int pkh(float a, float b) {
    __half2 h = __floats2half2_rn(a, b);
    return *(unsigned int*)&h;
}
// tanh-GELU in exp2 form
__device__ __forceinline__ float gelu_fast(float x) {
    float w = x * fmaf(x * x, 0.1029377202f, 2.302085565f);
    return x * __builtin_amdgcn_rcpf(1.0f + exp2f(-w));
}
__device__ __forceinline__ __half2 shfl8h(__half2 x, int m) {
    int xi = *(int*)&x;
    int yi = __shfl_xor(xi, m, 8);
    return *(__half2*)&yi;
}

// ============ K0: weight prep (fp32->fp16 MFMA A-frag order) + counter zero =====
// shorts: Wq@0 Wk@16384 Wv@32768 Wo@49152 W1@65536 W2@90112 (total 114688)
__global__ __launch_bounds__(256, 1) void k_prep(
    const float* __restrict__ Wq, const float* __restrict__ Wk, const float* __restrict__ Wv,
    const float* __restrict__ Wo, const float* __restrict__ W1, const float* __restrict__ W2,
    unsigned short* __restrict__ wsz, unsigned int* __restrict__ cnt)
{
    int idx = blockIdx.x * 256 + threadIdx.x;
    if (idx < 1024) cnt[idx] = 0;                 // tile-completion counters
    if (idx >= 28672) return;
    int f = idx >> 1;
    const int half = idx & 1;
    const float* W; unsigned short* dst; int M, KS, fl;
    if (f < 2048)       { W = Wq; dst = wsz;         M = 128; KS = 4; fl = f; }
    else if (f < 4096)  { W = Wk; dst = wsz + 16384; M = 128; KS = 4; fl = f - 2048; }
    else if (f < 6144)  { W = Wv; dst = wsz + 32768; M = 128; KS = 4; fl = f - 4096; }
    else if (f < 8192)  { W = Wo; dst = wsz + 49152; M = 128; KS = 4; fl = f - 6144; }
    else if (f < 11264) { W = W1; dst = wsz + 65536; M = 192; KS = 4; fl = f - 8192; }
    else                { W = W2; dst = wsz + 90112; M = 128; KS = 6; fl = f - 11264; }
    const int l  = fl & 63;
    const int ks = (fl >> 6) % KS;
    const int ct = (fl >> 6) / KS;
    const int k0 = ks * 32 + (l >> 4) * 8 + half * 4;
    const int col = ct * 16 + (l & 15);
    unsigned short tmp[4];
    #pragma unroll
    for (int j = 0; j < 4; ++j) {
        __half hh = __float2half(W[(size_t)(k0 + j) * M + col]);
        tmp[j] = *(unsigned short*)&hh;
    }
    ((uint2*)dst)[fl * 2 + half] = *(uint2*)tmp;
}

// ============ K1: QKV projection — frags from global; K|V interleaved out =======
__global__ __launch_bounds__(256, 4) void k_qkv(
    const float* __restrict__ feat, const unsigned short* __restrict__ wsz,
    unsigned short* __restrict__ Qb, unsigned short* __restrict__ KVb, int n)
{
    const int w = threadIdx.x >> 6, lane = threadIdx.x & 63;
    const int lrow = lane & 15, kgrp = lane >> 4;
    const int node = blockIdx.x * 64 + w * 16 + lrow;
    const bool valid = node < n;

    f16x8 bfr[4];
    #pragma unroll
    for (int ks = 0; ks < 4; ++ks) {
        float4 lo = make_float4(0.f, 0.f, 0.f, 0.f), hi = lo;
        if (valid) {
            const float* p = feat + (size_t)node * 128 + ks * 32 + kgrp * 8;
            lo = *(const float4*)p;
            hi = *(const float4*)(p + 4);
        }
        f16x8 b;
        b[0] = (_Float16)lo.x; b[1] = (_Float16)lo.y; b[2] = (_Float16)lo.z; b[3] = (_Float16)lo.w;
        b[4] = (_Float16)hi.x; b[5] = (_Float16)hi.y; b[6] = (_Float16)hi.z; b[7] = (_Float16)hi.w;
        bfr[ks] = b;
    }

    for (int mat = 0; mat < 3; ++mat) {
        const unsigned short* wb = wsz + mat * 16384;
        f32x4 acc[8];
        #pragma unroll
        for (int ct = 0; ct < 8; ++ct) acc[ct] = (f32x4){0.f, 0.f, 0.f, 0.f};
        #pragma unroll
        for (int ct = 0; ct < 8; ++ct)
            #pragma unroll
            for (int ks = 0; ks < 4; ++ks) {
                f16x8 afr = *(const f16x8*)(wb + ((size_t)(ct * 4 + ks) * 64 + lane) * 8);
                acc[ct] = __builtin_amdgcn_mfma_f32_16x16x32_f16(afr, bfr[ks], acc[ct], 0, 0, 0);
            }
        if (valid) {
            unsigned short* O = (mat == 0) ? (Qb + (size_t)node * 128)
                              : (KVb + (size_t)node * 256 + (mat == 2 ? 128 : 0));
            #pragma unroll
            for (int ct = 0; ct < 8; ++ct) {
                int col = ct * 16 + kgrp * 4;
                *((uint2*)(O + col)) =
                    make_uint2(pkh(acc[ct][0], acc[ct][1]), pkh(acc[ct][2], acc[ct][3]));
            }
        }
    }
}

// ============ K2: merged attention + tail, producer-consumer per 64-row tile ====
// Grid = tiles*17. Per tile t: sub-blocks r=0..15 do attention (4 nodes each),
// release-increment cnt[t]; sub-block r=16 acquire-spins until cnt[t]==target,
// then runs the fused tail for the tile. Deadlock-free: tail blocks (<=782)
// can never fill all resident slots; no dispatch-order assumption (G16).
__global__ __launch_bounds__(256, 6) void k_merged(
    const unsigned short* __restrict__ Qb, const unsigned short* __restrict__ KVb,
    const int* __restrict__ knn, const float* __restrict__ dist,
    unsigned short* __restrict__ attf, unsigned int* __restrict__ cnt,
    const float* __restrict__ feat, const unsigned short* __restrict__ wsz,
    const float* __restrict__ bo, const float* __restrict__ g1, const float* __restrict__ b1ln,
    const float* __restrict__ b1f, const float* __restrict__ b2f,
    const float* __restrict__ g2, const float* __restrict__ b2ln,
    float* __restrict__ out, int n)
{
    __shared__ __align__(16) unsigned short hls[12288];   // tail: X frags then H frags
    const int t = blockIdx.x / 17;
    const int r17 = blockIdx.x % 17;
    const int tid = threadIdx.x;
    const int w = tid >> 6, lane = tid & 63;
    const int lrow = lane & 15, kgrp = lane >> 4;

    if (r17 < 16) {
        // ---------------- attention sub-block: 4 nodes ----------------
        const int node0 = (t * 16 + r17) * 4;
        if (node0 >= n) return;                            // whole block idle
        const int node = node0 + w;
        const int h = lane >> 3, rr8 = lane & 7;
        const float L2E = 1.4426950408889634f;
        const float hsl = exp2f(-(float)(h + 1)) * L2E;

        if (node < n) {
            int idx[4]; float sdl[4];
            #pragma unroll
            for (int jj = 0; jj < 4; ++jj) {
                int j = rr8 + jj * 8;
                idx[jj] = knn[(size_t)node * 32 + j];
                sdl[jj] = dist[(size_t)node * 32 + j] * hsl;
            }
            const unsigned short* qp = Qb + (size_t)node * 128 + h * 16;
            __half2 q2[8];
            *((uint4*)&q2[0]) = *(const uint4*)qp;
            *((uint4*)&q2[4]) = *(const uint4*)(qp + 8);

            uint4 k0[4], k1[4], v0[4], v1[4];
            #pragma unroll
            for (int jj = 0; jj < 4; ++jj) {
                const unsigned short* kvp = KVb + (size_t)idx[jj] * 256 + h * 16;
                k0[jj] = *(const uint4*)kvp;
                k1[jj] = *(const uint4*)(kvp + 8);
                v0[jj] = *(const uint4*)(kvp + 128);
                v1[jj] = *(const uint4*)(kvp + 136);
            }

            float ap[4], an[4];
            #pragma unroll
            for (int jj = 0; jj < 4; ++jj) {
                const __half2* ka = (const __half2*)&k0[jj];
                const __half2* kb = (const __half2*)&k1[jj];
                __half2 s0 = __hmul2(q2[0], ka[0]);
                s0 = __hfma2(q2[1], ka[1], s0);
                s0 = __hfma2(q2[2], ka[2], s0);
                s0 = __hfma2(q2[3], ka[3], s0);
                __half2 s1 = __hmul2(q2[4], kb[0]);
                s1 = __hfma2(q2[5], kb[1], s1);
                s1 = __hfma2(q2[6], kb[2], s1);
                s1 = __hfma2(q2[7], kb[3], s1);
                float s = __low2float(s0) + __high2float(s0) + __low2float(s1) + __high2float(s1);
                float rawl = s * (0.25f * L2E);
                ap[jj] = rawl - sdl[jj];
                an[jj] = (-rawl - sdl[jj]) * (1.0f / 0.6f);
            }

            float mp = fmaxf(fmaxf(ap[0], ap[1]), fmaxf(ap[2], ap[3]));
            float mn = fmaxf(fmaxf(an[0], an[1]), fmaxf(an[2], an[3]));
            #pragma unroll
            for (int msk = 1; msk < 8; msk <<= 1) {
                mp = fmaxf(mp, __shfl_xor(mp, msk, 8));
                mn = fmaxf(mn, __shfl_xor(mn, msk, 8));
            }
            float ep[4], en[4], sp = 0.f, sn = 0.f;
            #pragma unroll
            for (int jj = 0; jj < 4; ++jj) {
                ep[jj] = exp2f(ap[jj] - mp); sp += ep[jj];
                en[jj] = exp2f(an[jj] - mn); sn += en[jj];
            }
            #pragma unroll
            for (int msk = 1; msk < 8; msk <<= 1) {
                sp += __shfl_xor(sp, msk, 8);
                sn += __shfl_xor(sn, msk, 8);
            }
            const float isp = 1.0f / sp;
            const float isn = 1.5f / sn;

            __half2 acc2[8];
            #pragma unroll
            for (int i = 0; i < 8; ++i) acc2[i] = __float2half2_rn(0.f);
            #pragma unroll
            for (int jj = 0; jj < 4; ++jj) {
                float wgt = ep[jj] * isp - en[jj] * isn;
                __half2 w2 = __float2half2_rn(wgt);
                const __half2* va = (const __half2*)&v0[jj];
                const __half2* vb = (const __half2*)&v1[jj];
                acc2[0] = __hfma2(w2, va[0], acc2[0]);
                acc2[1] = __hfma2(w2, va[1], acc2[1]);
                acc2[2] = __hfma2(w2, va[2], acc2[2]);
                acc2[3] = __hfma2(w2, va[3], acc2[3]);
                acc2[4] = __hfma2(w2, vb[0], acc2[4]);
                acc2[5] = __hfma2(w2, vb[1], acc2[5]);
                acc2[6] = __hfma2(w2, vb[2], acc2[6]);
                acc2[7] = __hfma2(w2, vb[3], acc2[7]);
            }
            #pragma unroll
            for (int i = 0; i < 8; ++i) {
                acc2[i] = __hadd2(acc2[i], shfl8h(acc2[i], 1));
                acc2[i] = __hadd2(acc2[i], shfl8h(acc2[i], 2));
                acc2[i] = __hadd2(acc2[i], shfl8h(acc2[i], 4));
            }
            if (rr8 == 0) {
                const int g = node >> 4, lr = node & 15;
                unsigned short* op = attf + (size_t)g * 2048 + (h >> 1) * 512 + (h & 1) * 256 + lr * 8;
                *((uint4*)op)         = *(uint4*)&acc2[0];
                *((uint4*)(op + 128)) = *(uint4*)&acc2[4];
            }
        }
        __syncthreads();                                   // all waves' stores issued+drained
        if (tid == 0) {
            __threadfence();                               // device-scope release of attf
            __hip_atomic_fetch_add(&cnt[t], 1u, __ATOMIC_RELEASE, __HIP_MEMORY_SCOPE_AGENT);
        }
        return;
    }

    // ---------------- tail sub-block for tile t ----------------
    {
        const int rem = n - t * 64;
        if (rem <= 0) return;
        const unsigned int target = (unsigned int)min(16, (rem + 3) >> 2);
        if (tid == 0) {
            while (__hip_atomic_load(&cnt[t], __ATOMIC_ACQUIRE, __HIP_MEMORY_SCOPE_AGENT) < target)
                __builtin_amdgcn_s_sleep(2);
        }
        __syncthreads();                                   // attf for tile t now visible
    }
    const int node = t * 64 + w * 16 + lrow;
    const bool valid = node < n;
    const int g = t * 4 + w;

    // ---- GEMM1: X = att @ Wo + bo + feat ----
    f16x8 bfr[6];
    #pragma unroll
    for (int ks = 0; ks < 4; ++ks) {
        uint4 u = make_uint4(0u, 0u, 0u, 0u);
        if (valid) u = *(const uint4*)(attf + (size_t)g * 2048 + (ks * 4 + kgrp) * 128 + lrow * 8);
        bfr[ks] = *(f16x8*)&u;
    }
    const unsigned short* wo = wsz + 49152;
    f32x4 X[8];
    #pragma unroll
    for (int ct = 0; ct < 8; ++ct) {
        X[ct] = (f32x4){0.f, 0.f, 0.f, 0.f};
        #pragma unroll
        for (int ks = 0; ks < 4; ++ks) {
            f16x8 afr = *(const f16x8*)(wo + ((size_t)(ct * 4 + ks) * 64 + lane) * 8);
            X[ct] = __builtin_amdgcn_mfma_f32_16x16x32_f16(afr, bfr[ks], X[ct], 0, 0, 0);
        }
    }
    #pragma unroll
    for (int ct = 0; ct < 8; ++ct) {
        int col = ct * 16 + kgrp * 4;
        float4 bv = *((const float4*)(bo + col));
        float4 fr = make_float4(0.f, 0.f, 0.f, 0.f);
        if (valid) fr = *((const float4*)(feat + (size_t)node * 128 + col));
        X[ct][0] += bv.x + fr.x; X[ct][1] += bv.y + fr.y;
        X[ct][2] += bv.z + fr.z; X[ct][3] += bv.w + fr.w;
    }
    float s = 0.f;
    #pragma unroll
    for (int ct = 0; ct < 8; ++ct) s += X[ct][0] + X[ct][1] + X[ct][2] + X[ct][3];
    s += __shfl_xor(s, 16); s += __shfl_xor(s, 32);
    const float mu1 = s * (1.0f / 128.0f);
    float s2 = 0.f;
    #pragma unroll
    for (int ct = 0; ct < 8; ++ct)
        #pragma unroll
        for (int rr = 0; rr < 4; ++rr) { float d = X[ct][rr] - mu1; s2 = fmaf(d, d, s2); }
    s2 += __shfl_xor(s2, 16); s2 += __shfl_xor(s2, 32);
    const float rs1 = rsqrtf(s2 * (1.0f / 128.0f) + 1e-5f);

    uint2 xnh[8];
    #pragma unroll
    for (int ct = 0; ct < 8; ++ct) {
        int col = ct * 16 + kgrp * 4;
        float4 gg = *((const float4*)(g1 + col));
        float4 bb = *((const float4*)(b1ln + col));
        float x0 = (X[ct][0] - mu1) * rs1 * gg.x + bb.x;
        float x1 = (X[ct][1] - mu1) * rs1 * gg.y + bb.y;
        float x2 = (X[ct][2] - mu1) * rs1 * gg.z + bb.z;
        float x3 = (X[ct][3] - mu1) * rs1 * gg.w + bb.w;
        xnh[ct] = make_uint2(pkh(x0, x1), pkh(x2, x3));
        int ks4 = col >> 5, kg = (col & 31) >> 3, jb = col & 7;
        *((uint2*)&hls[w * 2048 + (ks4 * 4 + kg) * 128 + lrow * 8 + jb]) = xnh[ct];
    }
    __syncthreads();
    #pragma unroll
    for (int ks = 0; ks < 4; ++ks)
        bfr[ks] = *(const f16x8*)&hls[w * 2048 + (ks * 4 + kgrp) * 128 + lrow * 8];
    __syncthreads();

    // ---- GEMM2: H = gelu(X@W1 + b1) -> LDS frags ----
    const unsigned short* w1 = wsz + 65536;
    #pragma unroll
    for (int ct = 0; ct < 12; ++ct) {
        f32x4 acc = (f32x4){0.f, 0.f, 0.f, 0.f};
        #pragma unroll
        for (int ks = 0; ks < 4; ++ks) {
            f16x8 afr = *(const f16x8*)(w1 + ((size_t)(ct * 4 + ks) * 64 + lane) * 8);
            acc = __builtin_amdgcn_mfma_f32_16x16x32_f16(afr, bfr[ks], acc, 0, 0, 0);
        }
        int col = ct * 16 + kgrp * 4;
        float4 bv = *((const float4*)(b1f + col));
        float h0 = gelu_fast(acc[0] + bv.x), h1 = gelu_fast(acc[1] + bv.y);
        float h2 = gelu_fast(acc[2] + bv.z), h3 = gelu_fast(acc[3] + bv.w);
        int ks6 = col >> 5, kg = (col & 31) >> 3, jb = col & 7;
        *((uint2*)&hls[w * 3072 + (ks6 * 4 + kg) * 128 + lrow * 8 + jb]) =
            make_uint2(pkh(h0, h1), pkh(h2, h3));
    }
    __syncthreads();
    f16x8 bfh[6];
    #pragma unroll
    for (int ks = 0; ks < 6; ++ks)
        bfh[ks] = *(const f16x8*)&hls[w * 3072 + (ks * 4 + kgrp) * 128 + lrow * 8];

    // ---- GEMM3: Y = H@W2 + b2 + X; LN2 ----
    const unsigned short* w2 = wsz + 90112;
    f32x4 Y[8];
    #pragma unroll
    for (int ct = 0; ct < 8; ++ct) {
        Y[ct] = (f32x4){0.f, 0.f, 0.f, 0.f};
        #pragma unroll
        for (int ks = 0; ks < 6; ++ks) {
            f16x8 afr = *(const f16x8*)(w2 + ((size_t)(ct * 6 + ks) * 64 + lane) * 8);
            Y[ct] = __builtin_amdgcn_mfma_f32_16x16x32_f16(afr, bfh[ks], Y[ct], 0, 0, 0);
        }
    }
    #pragma unroll
    for (int ct = 0; ct < 8; ++ct) {
        int col = ct * 16 + kgrp * 4;
        float4 bv = *((const float4*)(b2f + col));
        __half2 x01 = *(__half2*)&xnh[ct].x, x23 = *(__half2*)&xnh[ct].y;
        Y[ct][0] += bv.x + __low2float(x01);
        Y[ct][1] += bv.y + __high2float(x01);
        Y[ct][2] += bv.z + __low2float(x23);
        Y[ct][3] += bv.w + __high2float(x23);
    }
    float t1 = 0.f;
    #pragma unroll
    for (int ct = 0; ct < 8; ++ct) t1 += Y[ct][0] + Y[ct][1] + Y[ct][2] + Y[ct][3];
    t1 += __shfl_xor(t1, 16); t1 += __shfl_xor(t1, 32);
    const float mu2 = t1 * (1.0f / 128.0f);
    float t2 = 0.f;
    #pragma unroll
    for (int ct = 0; ct < 8; ++ct)
        #pragma unroll
        for (int rr = 0; rr < 4; ++rr) { float d = Y[ct][rr] - mu2; t2 = fmaf(d, d, t2); }
    t2 += __shfl_xor(t2, 16); t2 += __shfl_xor(t2, 32);
    const float rs2 = rsqrtf(t2 * (1.0f / 128.0f) + 1e-5f);
    if (valid) {
        #pragma unroll
        for (int ct = 0; ct < 8; ++ct) {
            int col = ct * 16 + kgrp * 4;
            float4 gg = *((const float4*)(g2 + col));
            float4 bb = *((const float4*)(b2ln + col));
            float4 o;
            o.x = (Y[ct][0] - mu2) * rs2 * gg.x + bb.x;
            o.y = (Y[ct][1] - mu2) * rs2 * gg.y + bb.y;
            o.z = (Y[ct][2] - mu2) * rs2 * gg.z + bb.z;
            o.w = (Y[ct][3] - mu2) * rs2 * gg.w + bb.w;
            *((float4*)(out + (size_t)node * 128 + col)) = o;
        }
    }
}

// ============ launch ============================================================
extern "C" void kernel_launch(void* const* d_in, const int* in_sizes, int n_in,
                              void* d_out, int out_size, void* d_ws, size_t ws_size,
                              hipStream_t stream)
{
    const float* feat = (const float*)d_in[0];
    const int*   knn  = (const int*)d_in[1];
    const float* dist = (const float*)d_in[2];
    const float* Wq   = (const float*)d_in[3];
    const float* Wk   = (const float*)d_in[4];
    const float* Wv   = (const float*)d_in[5];
    const float* Wo   = (const float*)d_in[6];
    const float* bo   = (const float*)d_in[7];
    const float* g1   = (const float*)d_in[8];
    const float* b1ln = (const float*)d_in[9];
    const float* W1   = (const float*)d_in[10];
    const float* b1f  = (const float*)d_in[11];
    const float* W2   = (const float*)d_in[12];
    const float* b2f  = (const float*)d_in[13];
    const float* g2   = (const float*)d_in[14];
    const float* b2ln = (const float*)d_in[15];
    float* out = (float*)d_out;

    const int n = in_sizes[0] / 128;
    const size_t ND = (size_t)n * 128;
    if (ws_size < 8 * ND + 262144) return;

    unsigned short* Qb   = (unsigned short*)d_ws;   // ND fp16
    unsigned short* KVb  = Qb + ND;                 // 2*ND fp16, K|V interleaved per node
    unsigned short* attf = KVb + 2 * ND;            // ND fp16, fragment order
    unsigned short* Wsz  = attf + ND;               // 114688 fp16
    unsigned int*   cnt  = (unsigned int*)(Wsz + 114688);  // 1024 u32 (tile counters)

    const int tiles = (n + 63) / 64;
    k_prep  <<<112, 256, 0, stream>>>(Wq, Wk, Wv, Wo, W1, W2, Wsz, cnt);
    k_qkv   <<<(n + 63) / 64, 256, 0, stream>>>(feat, Wsz, Qb, KVb, n);
    k_merged<<<tiles * 17, 256, 0, stream>>>(Qb, KVb, knn, dist, attf, cnt, feat, Wsz,
                                             bo, g1, b1ln, b1f, b2f, g2, b2ln, out, n);
}

// Round 12
// 175.053 us; speedup vs baseline: 6.1902x; 6.1902x over previous
//
#include <hip/hip_runtime.h>
#include <hip/hip_fp16.h>
#include <cmath>

typedef __attribute__((ext_vector_type(8))) _Float16 f16x8;
typedef __attribute__((ext_vector_type(4))) float f32x4;

__device__ __forceinline__ unsigned int pkh(float a, float b) {
    __half2 h = __floats2half2_rn(a, b);
    return *(unsigned int*)&h;
}
// tanh-GELU in exp2 form: gelu(x) = x / (1 + exp2(-w)), w = 2.3020856*x*(1+0.044715x^2)
__device__ __forceinline__ float gelu_fast(float x) {
    float w = x * fmaf(x * x, 0.1029377202f, 2.302085565f);
    return x * __builtin_amdgcn_rcpf(1.0f + exp2f(-w));
}
__device__ __forceinline__ __half2 shfl8h(__half2 x, int m) {
    int xi = *(int*)&x;
    int yi = __shfl_xor(xi, m, 8);
    return *(__half2*)&yi;
}

// ============ K0: weight prep — fp32 -> fp16, MFMA A-fragment order =============
// frag(ct,ks,l,j) = W[ks*32 + (l>>4)*8 + j][ct*16 + (l&15)]  (A-operand = W^T tile)
// shorts: Wq@0 Wk@16384 Wv@32768 Wo@49152 W1@65536 W2@90112 (total 114688)
__global__ __launch_bounds__(256, 1) void k_prep(
    const float* __restrict__ Wq, const float* __restrict__ Wk, const float* __restrict__ Wv,
    const float* __restrict__ Wo, const float* __restrict__ W1, const float* __restrict__ W2,
    unsigned short* __restrict__ wsz)
{
    int idx = blockIdx.x * 256 + threadIdx.x;
    if (idx >= 28672) return;
    int f = idx >> 1;
    const int half = idx & 1;
    const float* W; unsigned short* dst; int M, KS, fl;
    if (f < 2048)       { W = Wq; dst = wsz;         M = 128; KS = 4; fl = f; }
    else if (f < 4096)  { W = Wk; dst = wsz + 16384; M = 128; KS = 4; fl = f - 2048; }
    else if (f < 6144)  { W = Wv; dst = wsz + 32768; M = 128; KS = 4; fl = f - 4096; }
    else if (f < 8192)  { W = Wo; dst = wsz + 49152; M = 128; KS = 4; fl = f - 6144; }
    else if (f < 11264) { W = W1; dst = wsz + 65536; M = 192; KS = 4; fl = f - 8192; }
    else                { W = W2; dst = wsz + 90112; M = 128; KS = 6; fl = f - 11264; }
    const int l  = fl & 63;
    const int ks = (fl >> 6) % KS;
    const int ct = (fl >> 6) / KS;
    const int k0 = ks * 32 + (l >> 4) * 8 + half * 4;
    const int col = ct * 16 + (l & 15);
    unsigned short tmp[4];
    #pragma unroll
    for (int j = 0; j < 4; ++j) {
        __half hh = __float2half(W[(size_t)(k0 + j) * M + col]);
        tmp[j] = *(unsigned short*)&hh;
    }
    ((uint2*)dst)[fl * 2 + half] = *(uint2*)tmp;
}

// ============ K1: QKV projection — frags from global; K|V interleaved out =======
__global__ __launch_bounds__(256, 4) void k_qkv(
    const float* __restrict__ feat, const unsigned short* __restrict__ wsz,
    unsigned short* __restrict__ Qb, unsigned short* __restrict__ KVb, int n)
{
    const int w = threadIdx.x >> 6, lane = threadIdx.x & 63;
    const int lrow = lane & 15, kgrp = lane >> 4;
    const int node = blockIdx.x * 64 + w * 16 + lrow;
    const bool valid = node < n;

    f16x8 bfr[4];
    #pragma unroll
    for (int ks = 0; ks < 4; ++ks) {
        float4 lo = make_float4(0.f, 0.f, 0.f, 0.f), hi = lo;
        if (valid) {
            const float* p = feat + (size_t)node * 128 + ks * 32 + kgrp * 8;
            lo = *(const float4*)p;
            hi = *(const float4*)(p + 4);
        }
        f16x8 b;
        b[0] = (_Float16)lo.x; b[1] = (_Float16)lo.y; b[2] = (_Float16)lo.z; b[3] = (_Float16)lo.w;
        b[4] = (_Float16)hi.x; b[5] = (_Float16)hi.y; b[6] = (_Float16)hi.z; b[7] = (_Float16)hi.w;
        bfr[ks] = b;
    }

    for (int mat = 0; mat < 3; ++mat) {
        const unsigned short* wb = wsz + mat * 16384;
        f32x4 acc[8];
        #pragma unroll
        for (int ct = 0; ct < 8; ++ct) acc[ct] = (f32x4){0.f, 0.f, 0.f, 0.f};
        #pragma unroll
        for (int ct = 0; ct < 8; ++ct)
            #pragma unroll
            for (int ks = 0; ks < 4; ++ks) {
                f16x8 afr = *(const f16x8*)(wb + ((size_t)(ct * 4 + ks) * 64 + lane) * 8);
                acc[ct] = __builtin_amdgcn_mfma_f32_16x16x32_f16(afr, bfr[ks], acc[ct], 0, 0, 0);
            }
        if (valid) {
            unsigned short* O = (mat == 0) ? (Qb + (size_t)node * 128)
                              : (KVb + (size_t)node * 256 + (mat == 2 ? 128 : 0));
            #pragma unroll
            for (int ct = 0; ct < 8; ++ct) {
                int col = ct * 16 + kgrp * 4;
                *((uint2*)(O + col)) =
                    make_uint2(pkh(acc[ct][0], acc[ct][1]), pkh(acc[ct][2], acc[ct][3]));
            }
        }
    }
}

// ============ K2: KNN attention — interleaved K|V gather; frag-order output =====
__global__ __launch_bounds__(256, 4) void k_attn(
    const unsigned short* __restrict__ Qb, const unsigned short* __restrict__ KVb,
    const int* __restrict__ knn, const float* __restrict__ dist,
    unsigned short* __restrict__ attf, int n)
{
    const int lane = threadIdx.x & 63;
    const int node = blockIdx.x * 4 + (threadIdx.x >> 6);
    if (node >= n) return;
    const int h = lane >> 3, r = lane & 7;
    const float L2E = 1.4426950408889634f;
    const float hsl = exp2f(-(float)(h + 1)) * L2E;     // head scaling in log2 units

    int idx[4]; float sdl[4];
    #pragma unroll
    for (int jj = 0; jj < 4; ++jj) {
        int j = r + jj * 8;
        idx[jj] = knn[(size_t)node * 32 + j];
        sdl[jj] = dist[(size_t)node * 32 + j] * hsl;
    }

    const unsigned short* qp = Qb + (size_t)node * 128 + h * 16;
    __half2 q2[8];
    *((uint4*)&q2[0]) = *(const uint4*)qp;
    *((uint4*)&q2[4]) = *(const uint4*)(qp + 8);

    uint4 k0[4], k1[4], v0[4], v1[4];
    #pragma unroll
    for (int jj = 0; jj < 4; ++jj) {
        const unsigned short* kvp = KVb + (size_t)idx[jj] * 256 + h * 16;
        k0[jj] = *(const uint4*)kvp;
        k1[jj] = *(const uint4*)(kvp + 8);
        v0[jj] = *(const uint4*)(kvp + 128);
        v1[jj] = *(const uint4*)(kvp + 136);
    }

    float ap[4], an[4];
    #pragma unroll
    for (int jj = 0; jj < 4; ++jj) {
        const __half2* ka = (const __half2*)&k0[jj];
        const __half2* kb = (const __half2*)&k1[jj];
        __half2 s0 = __hmul2(q2[0], ka[0]);
        s0 = __hfma2(q2[1], ka[1], s0);
        s0 = __hfma2(q2[2], ka[2], s0);
        s0 = __hfma2(q2[3], ka[3], s0);
        __half2 s1 = __hmul2(q2[4], kb[0]);
        s1 = __hfma2(q2[5], kb[1], s1);
        s1 = __hfma2(q2[6], kb[2], s1);
        s1 = __hfma2(q2[7], kb[3], s1);
        float s = __low2float(s0) + __high2float(s0) + __low2float(s1) + __high2float(s1);
        float rawl = s * (0.25f * L2E);                  // score * log2e
        ap[jj] = rawl - sdl[jj];
        an[jj] = (-rawl - sdl[jj]) * (1.0f / 0.6f);
    }

    float mp = fmaxf(fmaxf(ap[0], ap[1]), fmaxf(ap[2], ap[3]));
    float mn = fmaxf(fmaxf(an[0], an[1]), fmaxf(an[2], an[3]));
    #pragma unroll
    for (int msk = 1; msk < 8; msk <<= 1) {
        mp = fmaxf(mp, __shfl_xor(mp, msk, 8));
        mn = fmaxf(mn, __shfl_xor(mn, msk, 8));
    }
    float ep[4], en[4], sp = 0.f, sn = 0.f;
    #pragma unroll
    for (int jj = 0; jj < 4; ++jj) {
        ep[jj] = exp2f(ap[jj] - mp); sp += ep[jj];
        en[jj] = exp2f(an[jj] - mn); sn += en[jj];
    }
    #pragma unroll
    for (int msk = 1; msk < 8; msk <<= 1) {
        sp += __shfl_xor(sp, msk, 8);
        sn += __shfl_xor(sn, msk, 8);
    }
    const float isp = 1.0f / sp;
    const float isn = 1.5f / sn;

    __half2 acc2[8];
    #pragma unroll
    for (int i = 0; i < 8; ++i) acc2[i] = __float2half2_rn(0.f);
    #pragma unroll
    for (int jj = 0; jj < 4; ++jj) {
        float wgt = ep[jj] * isp - en[jj] * isn;
        __half2 w2 = __float2half2_rn(wgt);
        const __half2* va = (const __half2*)&v0[jj];
        const __half2* vb = (const __half2*)&v1[jj];
        acc2[0] = __hfma2(w2, va[0], acc2[0]);
        acc2[1] = __hfma2(w2, va[1], acc2[1]);
        acc2[2] = __hfma2(w2, va[2], acc2[2]);
        acc2[3] = __hfma2(w2, va[3], acc2[3]);
        acc2[4] = __hfma2(w2, vb[0], acc2[4]);
        acc2[5] = __hfma2(w2, vb[1], acc2[5]);
        acc2[6] = __hfma2(w2, vb[2], acc2[6]);
        acc2[7] = __hfma2(w2, vb[3], acc2[7]);
    }
    #pragma unroll
    for (int i = 0; i < 8; ++i) {
        acc2[i] = __hadd2(acc2[i], shfl8h(acc2[i], 1));
        acc2[i] = __hadd2(acc2[i], shfl8h(acc2[i], 2));
        acc2[i] = __hadd2(acc2[i], shfl8h(acc2[i], 4));
    }
    if (r == 0) {
        // fragment-order store (matches tail's B-fragment read)
        const int g = node >> 4, lrow = node & 15;
        unsigned short* op = attf + (size_t)g * 2048 + (h >> 1) * 512 + (h & 1) * 256 + lrow * 8;
        *((uint4*)op)         = *(uint4*)&acc2[0];
        *((uint4*)(op + 128)) = *(uint4*)&acc2[4];
    }
}

// ============ K3: fused tail — X=LN1(att@Wo+bo+feat); H=gelu(X@W1+b1);
//   out=LN2(H@W2+b2+X). 64 rows/block; weights from global (L2-hot).
//   LDS regions are DISJOINT and wave-private (X: 16KB @0, H: 24KB @8192 shorts)
//   -> zero __syncthreads; per-wave in-order DS ops give all needed ordering. ====
__global__ __launch_bounds__(256, 4) void k_tail(
    const unsigned short* __restrict__ attf, const float* __restrict__ feat,
    const unsigned short* __restrict__ wsz,
    const float* __restrict__ bo, const float* __restrict__ g1, const float* __restrict__ b1ln,
    const float* __restrict__ b1f, const float* __restrict__ b2f,
    const float* __restrict__ g2, const float* __restrict__ b2ln,
    float* __restrict__ out, int n)
{
    __shared__ __align__(16) unsigned short hls[20480];   // 40 KB: X[0,8192) H[8192,20480)
    const int tid = threadIdx.x;
    const int w = tid >> 6, lane = tid & 63;
    const int lrow = lane & 15, kgrp = lane >> 4;
    const int node = blockIdx.x * 64 + w * 16 + lrow;
    const bool valid = node < n;
    const int g = blockIdx.x * 4 + w;
    unsigned short* xls = hls + w * 2048;                  // wave-private X frags
    unsigned short* hfl = hls + 8192 + w * 3072;           // wave-private H frags

    // ---- GEMM1: X = att @ Wo + bo + feat ----
    f16x8 bfr[6];
    #pragma unroll
    for (int ks = 0; ks < 4; ++ks) {
        uint4 u = make_uint4(0u, 0u, 0u, 0u);
        if (valid) u = *(const uint4*)(attf + (size_t)g * 2048 + (ks * 4 + kgrp) * 128 + lrow * 8);
        bfr[ks] = *(f16x8*)&u;
    }
    const unsigned short* wo = wsz + 49152;
    f32x4 X[8];
    #pragma unroll
    for (int ct = 0; ct < 8; ++ct) {
        X[ct] = (f32x4){0.f, 0.f, 0.f, 0.f};
        #pragma unroll
        for (int ks = 0; ks < 4; ++ks) {
            f16x8 afr = *(const f16x8*)(wo + ((size_t)(ct * 4 + ks) * 64 + lane) * 8);
            X[ct] = __builtin_amdgcn_mfma_f32_16x16x32_f16(afr, bfr[ks], X[ct], 0, 0, 0);
        }
    }
    #pragma unroll
    for (int ct = 0; ct < 8; ++ct) {
        int col = ct * 16 + kgrp * 4;
        float4 bv = *((const float4*)(bo + col));
        float4 fr = make_float4(0.f, 0.f, 0.f, 0.f);
        if (valid) fr = *((const float4*)(feat + (size_t)node * 128 + col));
        X[ct][0] += bv.x + fr.x; X[ct][1] += bv.y + fr.y;
        X[ct][2] += bv.z + fr.z; X[ct][3] += bv.w + fr.w;
    }
    // LN1: node's 128 values live in lanes {lane, lane^16, lane^32, lane^48}
    float s = 0.f;
    #pragma unroll
    for (int ct = 0; ct < 8; ++ct) s += X[ct][0] + X[ct][1] + X[ct][2] + X[ct][3];
    s += __shfl_xor(s, 16); s += __shfl_xor(s, 32);
    const float mu1 = s * (1.0f / 128.0f);
    float s2 = 0.f;
    #pragma unroll
    for (int ct = 0; ct < 8; ++ct)
        #pragma unroll
        for (int rr = 0; rr < 4; ++rr) { float d = X[ct][rr] - mu1; s2 = fmaf(d, d, s2); }
    s2 += __shfl_xor(s2, 16); s2 += __shfl_xor(s2, 32);
    const float rs1 = rsqrtf(s2 * (1.0f / 128.0f) + 1e-5f);

    #pragma unroll
    for (int ct = 0; ct < 8; ++ct) {
        int col = ct * 16 + kgrp * 4;
        float4 gg = *((const float4*)(g1 + col));
        float4 bb = *((const float4*)(b1ln + col));
        float x0 = (X[ct][0] - mu1) * rs1 * gg.x + bb.x;
        float x1 = (X[ct][1] - mu1) * rs1 * gg.y + bb.y;
        float x2 = (X[ct][2] - mu1) * rs1 * gg.z + bb.z;
        float x3 = (X[ct][3] - mu1) * rs1 * gg.w + bb.w;
        int ks4 = col >> 5, kg = (col & 31) >> 3, jb = col & 7;
        *((uint2*)&xls[(ks4 * 4 + kg) * 128 + lrow * 8 + jb]) =
            make_uint2(pkh(x0, x1), pkh(x2, x3));
    }
    // wave-private LDS: same-wave DS ordering, no barrier needed
    #pragma unroll
    for (int ks = 0; ks < 4; ++ks)
        bfr[ks] = *(const f16x8*)&xls[(ks * 4 + kgrp) * 128 + lrow * 8];

    // ---- GEMM2: H = gelu(X@W1 + b1) -> LDS frags ----
    const unsigned short* w1 = wsz + 65536;
    #pragma unroll
    for (int ct = 0; ct < 12; ++ct) {
        f32x4 acc = (f32x4){0.f, 0.f, 0.f, 0.f};
        #pragma unroll
        for (int ks = 0; ks < 4; ++ks) {
            f16x8 afr = *(const f16x8*)(w1 + ((size_t)(ct * 4 + ks) * 64 + lane) * 8);
            acc = __builtin_amdgcn_mfma_f32_16x16x32_f16(afr, bfr[ks], acc, 0, 0, 0);
        }
        int col = ct * 16 + kgrp * 4;
        float4 bv = *((const float4*)(b1f + col));
        float h0 = gelu_fast(acc[0] + bv.x), h1 = gelu_fast(acc[1] + bv.y);
        float h2 = gelu_fast(acc[2] + bv.z), h3 = gelu_fast(acc[3] + bv.w);
        int ks6 = col >> 5, kg = (col & 31) >> 3, jb = col & 7;
        *((uint2*)&hfl[(ks6 * 4 + kg) * 128 + lrow * 8 + jb]) =
            make_uint2(pkh(h0, h1), pkh(h2, h3));
    }
    f16x8 bfh[6];
    #pragma unroll
    for (int ks = 0; ks < 6; ++ks)
        bfh[ks] = *(const f16x8*)&hfl[(ks * 4 + kgrp) * 128 + lrow * 8];

    // ---- GEMM3: Y = H@W2 + b2 + X; LN2 (X residual re-read from live X region) --
    const unsigned short* w2 = wsz + 90112;
    f32x4 Y[8];
    #pragma unroll
    for (int ct = 0; ct < 8; ++ct) {
        Y[ct] = (f32x4){0.f, 0.f, 0.f, 0.f};
        #pragma unroll
        for (int ks = 0; ks < 6; ++ks) {
            f16x8 afr = *(const f16x8*)(w2 + ((size_t)(ct * 6 + ks) * 64 + lane) * 8);
            Y[ct] = __builtin_amdgcn_mfma_f32_16x16x32_f16(afr, bfh[ks], Y[ct], 0, 0, 0);
        }
    }
    #pragma unroll
    for (int ct = 0; ct < 8; ++ct) {
        int col = ct * 16 + kgrp * 4;
        float4 bv = *((const float4*)(b2f + col));
        int ks4 = col >> 5, kg = (col & 31) >> 3, jb = col & 7;
        uint2 xv = *((const uint2*)&xls[(ks4 * 4 + kg) * 128 + lrow * 8 + jb]);
        __half2 x01 = *(__half2*)&xv.x, x23 = *(__half2*)&xv.y;
        Y[ct][0] += bv.x + __low2float(x01);
        Y[ct][1] += bv.y + __high2float(x01);
        Y[ct][2] += bv.z + __low2float(x23);
        Y[ct][3] += bv.w + __high2float(x23);
    }
    float t1 = 0.f;
    #pragma unroll
    for (int ct = 0; ct < 8; ++ct) t1 += Y[ct][0] + Y[ct][1] + Y[ct][2] + Y[ct][3];
    t1 += __shfl_xor(t1, 16); t1 += __shfl_xor(t1, 32);
    const float mu2 = t1 * (1.0f / 128.0f);
    float t2 = 0.f;
    #pragma unroll
    for (int ct = 0; ct < 8; ++ct)
        #pragma unroll
        for (int rr = 0; rr < 4; ++rr) { float d = Y[ct][rr] - mu2; t2 = fmaf(d, d, t2); }
    t2 += __shfl_xor(t2, 16); t2 += __shfl_xor(t2, 32);
    const float rs2 = rsqrtf(t2 * (1.0f / 128.0f) + 1e-5f);
    if (valid) {
        #pragma unroll
        for (int ct = 0; ct < 8; ++ct) {
            int col = ct * 16 + kgrp * 4;
            float4 gg = *((const float4*)(g2 + col));
            float4 bb = *((const float4*)(b2ln + col));
            float4 o;
            o.x = (Y[ct][0] - mu2) * rs2 * gg.x + bb.x;
            o.y = (Y[ct][1] - mu2) * rs2 * gg.y + bb.y;
            o.z = (Y[ct][2] - mu2) * rs2 * gg.z + bb.z;
            o.w = (Y[ct][3] - mu2) * rs2 * gg.w + bb.w;
            *((float4*)(out + (size_t)node * 128 + col)) = o;
        }
    }
}

// ============ launch ============================================================
extern "C" void kernel_launch(void* const* d_in, const int* in_sizes, int n_in,
                              void* d_out, int out_size, void* d_ws, size_t ws_size,
                              hipStream_t stream)
{
    const float* feat = (const float*)d_in[0];
    const int*   knn  = (const int*)d_in[1];
    const float* dist = (const float*)d_in[2];
    const float* Wq   = (const float*)d_in[3];
    const float* Wk   = (const float*)d_in[4];
    const float* Wv   = (const float*)d_in[5];
    const float* Wo   = (const float*)d_in[6];
    const float* bo   = (const float*)d_in[7];
    const float* g1   = (const float*)d_in[8];
    const float* b1ln = (const float*)d_in[9];
    const float* W1   = (const float*)d_in[10];
    const float* b1f  = (const float*)d_in[11];
    const float* W2   = (const float*)d_in[12];
    const float* b2f  = (const float*)d_in[13];
    const float* g2   = (const float*)d_in[14];
    const float* b2ln = (const float*)d_in[15];
    float* out = (float*)d_out;

    const int n = in_sizes[0] / 128;
    const size_t ND = (size_t)n * 128;
    if (ws_size < 8 * ND + 262144) return;

    unsigned short* Qb   = (unsigned short*)d_ws;   // ND fp16
    unsigned short* KVb  = Qb + ND;                 // 2*ND fp16, K|V interleaved per node
    unsigned short* attf = KVb + 2 * ND;            // ND fp16, fragment order
    unsigned short* Wsz  = attf + ND;               // 114688 fp16

    k_prep<<<112, 256, 0, stream>>>(Wq, Wk, Wv, Wo, W1, W2, Wsz);
    k_qkv <<<(n + 63) / 64, 256, 0, stream>>>(feat, Wsz, Qb, KVb, n);
    k_attn<<<(n + 3) / 4,   256, 0, stream>>>(Qb, KVb, knn, dist, attf, n);
    k_tail<<<(n + 63) / 64, 256, 0, stream>>>(attf, feat, Wsz, bo, g1, b1ln, b1f, b2f,
                                              g2, b2ln, out, n);
}